// Round 1
// baseline (2858.842 us; speedup 1.0000x reference)
//
#include <hip/hip_runtime.h>
#include <hip/hip_bf16.h>
#include <math.h>

#define D_    1152
#define H_    16
#define HD    72
#define E_    8
#define MLPH  4608
#define B_    8
#define S_    256
#define N_TOK 2048

// ---------------------------------------------------------------------------
// mod = silu(c) @ adaln_w + adaln_b      (8 x 4608)
// grid (4608/256, 8), block 256
__global__ void adaln_kernel(const float* __restrict__ c, const float* __restrict__ w,
                             const float* __restrict__ bias, float* __restrict__ mod) {
    __shared__ float sc[D_];
    int b = blockIdx.y;
    int j = blockIdx.x * 256 + threadIdx.x;
    for (int d = threadIdx.x; d < D_; d += 256) {
        float v = c[b * D_ + d];
        sc[d] = v / (1.f + __expf(-v));
    }
    __syncthreads();
    float acc = bias[j];
    for (int d = 0; d < D_; ++d)
        acc += sc[d] * w[(size_t)d * (4 * D_) + j];
    mod[b * (4 * D_) + j] = acc;
}

// ---------------------------------------------------------------------------
// LayerNorm (biased var, eps=1e-6); optionally apply adaLN modulation:
// out = ln(x) * (1 + scale_msa) + shift_msa
// grid 2048, block 256
__global__ void ln_kernel(const float* __restrict__ x, const float* __restrict__ mod,
                          float* __restrict__ out, int use_mod) {
    int n = blockIdx.x;
    int b = n / S_;
    const float* xr = x + (size_t)n * D_;
    float s = 0.f, s2 = 0.f;
    for (int d = threadIdx.x; d < D_; d += 256) {
        float v = xr[d];
        s += v; s2 += v * v;
    }
    for (int off = 32; off > 0; off >>= 1) {
        s  += __shfl_down(s,  off);
        s2 += __shfl_down(s2, off);
    }
    __shared__ float wsum[4], wsum2[4], stats[2];
    int wid = threadIdx.x >> 6, lane = threadIdx.x & 63;
    if (lane == 0) { wsum[wid] = s; wsum2[wid] = s2; }
    __syncthreads();
    if (threadIdx.x == 0) {
        float ts = 0.f, ts2 = 0.f;
        for (int i = 0; i < 4; ++i) { ts += wsum[i]; ts2 += wsum2[i]; }
        float m = ts / D_;
        float var = ts2 / D_ - m * m;
        stats[0] = m; stats[1] = rsqrtf(var + 1e-6f);
    }
    __syncthreads();
    float m = stats[0], inv = stats[1];
    for (int d = threadIdx.x; d < D_; d += 256) {
        float v = (xr[d] - m) * inv;
        if (use_mod)
            v = v * (1.f + mod[b * (4 * D_) + D_ + d]) + mod[b * (4 * D_) + d];
        out[(size_t)n * D_ + d] = v;
    }
}

// ---------------------------------------------------------------------------
// Dense fp32 GEMM: C[M,N] = A[M,K] @ B[K,N] + bias[N]
// 64x64 tile, 256 threads, 4x4 per-thread micro-tile, K-tile 16.
// M,N,K all multiples of 64/64/16 at our call sites.
__global__ __launch_bounds__(256) void gemm_bias(
    const float* __restrict__ A, const float* __restrict__ B,
    const float* __restrict__ bias, float* __restrict__ C,
    int M, int N, int K) {
    __shared__ float As[16][64];
    __shared__ float Bs[16][64];
    int tid = threadIdx.x;
    int tx = tid & 15, ty = tid >> 4;
    int m0 = blockIdx.y * 64, n0 = blockIdx.x * 64;
    int lm = tid >> 2, lk4 = (tid & 3) * 4;
    int lkb = tid >> 4, lnb = (tid & 15) * 4;
    const float* Arow = A + (size_t)(m0 + lm) * K;
    float acc[4][4] = {};
    for (int k0 = 0; k0 < K; k0 += 16) {
        float4 av = *(const float4*)(Arow + k0 + lk4);
        float4 bv = *(const float4*)(B + (size_t)(k0 + lkb) * N + n0 + lnb);
        As[lk4 + 0][lm] = av.x; As[lk4 + 1][lm] = av.y;
        As[lk4 + 2][lm] = av.z; As[lk4 + 3][lm] = av.w;
        *(float4*)&Bs[lkb][lnb] = bv;
        __syncthreads();
#pragma unroll
        for (int k = 0; k < 16; ++k) {
            float a[4], b[4];
#pragma unroll
            for (int i = 0; i < 4; ++i) a[i] = As[k][ty * 4 + i];
#pragma unroll
            for (int j = 0; j < 4; ++j) b[j] = Bs[k][tx * 4 + j];
#pragma unroll
            for (int i = 0; i < 4; ++i)
#pragma unroll
                for (int j = 0; j < 4; ++j) acc[i][j] += a[i] * b[j];
        }
        __syncthreads();
    }
#pragma unroll
    for (int i = 0; i < 4; ++i) {
        int row = m0 + ty * 4 + i;
        int col0 = n0 + tx * 4;
        float4 o;
        o.x = acc[i][0] + bias[col0 + 0];
        o.y = acc[i][1] + bias[col0 + 1];
        o.z = acc[i][2] + bias[col0 + 2];
        o.w = acc[i][3] + bias[col0 + 3];
        *(float4*)&C[(size_t)row * N + col0] = o;
    }
}

// ---------------------------------------------------------------------------
// Attention: one block per (q-tile of 16, head, batch). S=256 keys in 4x64 chunks.
__global__ __launch_bounds__(256) void attn_kernel(const float* __restrict__ qkv,
                                                   float* __restrict__ o) {
    int qt = blockIdx.x;  // 0..15
    int hh = blockIdx.y;  // 0..15
    int b  = blockIdx.z;  // 0..7
    __shared__ float qs[16][HD];
    __shared__ float kv[64][73];
    __shared__ float sc[16][256];
    __shared__ float rows[16];
    int tid = threadIdx.x;

    for (int i = tid; i < 16 * HD; i += 256) {
        int qi = i / HD, dd = i % HD;
        int n = b * S_ + qt * 16 + qi;
        qs[qi][dd] = qkv[(size_t)n * 3456 + hh * HD + dd];
    }
    int jj = tid & 63;
    int qg = tid >> 6;  // 0..3
    for (int c = 0; c < 4; ++c) {
        for (int i = tid; i < 64 * HD; i += 256) {
            int j = i / HD, dd = i % HD;
            int n = b * S_ + c * 64 + j;
            kv[j][dd] = qkv[(size_t)n * 3456 + D_ + hh * HD + dd];
        }
        __syncthreads();
#pragma unroll
        for (int qq = 0; qq < 4; ++qq) {
            int qi = qg * 4 + qq;
            float acc = 0.f;
            for (int dd = 0; dd < HD; ++dd) acc += qs[qi][dd] * kv[jj][dd];
            sc[qi][c * 64 + jj] = acc * 0.11785113019775793f;  // 72^-0.5
        }
        __syncthreads();
    }
    if (tid < 16) {
        float m = -1e30f;
        for (int j = 0; j < 256; ++j) m = fmaxf(m, sc[tid][j]);
        float s = 0.f;
        for (int j = 0; j < 256; ++j) {
            float e = __expf(sc[tid][j] - m);
            sc[tid][j] = e; s += e;
        }
        rows[tid] = s;
    }
    __syncthreads();
    float acc[5] = {0.f, 0.f, 0.f, 0.f, 0.f};
    for (int c = 0; c < 4; ++c) {
        for (int i = tid; i < 64 * HD; i += 256) {
            int j = i / HD, dd = i % HD;
            int n = b * S_ + c * 64 + j;
            kv[j][dd] = qkv[(size_t)n * 3456 + 2 * D_ + hh * HD + dd];
        }
        __syncthreads();
#pragma unroll
        for (int oi = 0; oi < 5; ++oi) {
            int oidx = oi * 256 + tid;
            if (oidx < 16 * HD) {
                int qi = oidx / HD, dd = oidx % HD;
                float a = acc[oi];
                for (int j = 0; j < 64; ++j) a += sc[qi][c * 64 + j] * kv[j][dd];
                acc[oi] = a;
            }
        }
        __syncthreads();
    }
    for (int oi = 0; oi < 5; ++oi) {
        int oidx = oi * 256 + tid;
        if (oidx < 16 * HD) {
            int qi = oidx / HD, dd = oidx % HD;
            int n = b * S_ + qt * 16 + qi;
            o[(size_t)n * D_ + hh * HD + dd] = acc[oi] / rows[qi];
        }
    }
}

// ---------------------------------------------------------------------------
// xa = x + gate_msa * o2
__global__ void residual1(const float* __restrict__ x, const float* __restrict__ o2,
                          const float* __restrict__ mod, float* __restrict__ xa) {
    int i = blockIdx.x * 256 + threadIdx.x;
    int n = i / D_, d = i % D_;
    int b = n / S_;
    xa[i] = x[i] + mod[b * (4 * D_) + 2 * D_ + d] * o2[i];
}

// ---------------------------------------------------------------------------
// Router: logits = nx @ gate_w + gate_b; top-2 + softmax; build expert lists.
// grid 2048, block 64 (one wave per token)
__global__ void router_kernel(const float* __restrict__ nx, const float* __restrict__ gw,
                              const float* __restrict__ gb, int* __restrict__ counts,
                              int* __restrict__ etok, int* __restrict__ eslot,
                              int* __restrict__ tslot, float* __restrict__ tscore) {
    int n = blockIdx.x;
    int lane = threadIdx.x;
    float acc[E_] = {};
    for (int d = lane; d < D_; d += 64) {
        float v = nx[(size_t)n * D_ + d];
#pragma unroll
        for (int e = 0; e < E_; ++e) acc[e] += v * gw[d * E_ + e];
    }
#pragma unroll
    for (int e = 0; e < E_; ++e)
        for (int off = 32; off > 0; off >>= 1) acc[e] += __shfl_down(acc[e], off);
    if (lane == 0) {
        float lg[E_];
#pragma unroll
        for (int e = 0; e < E_; ++e) lg[e] = acc[e] + gb[e];
        int i0 = 0;
        for (int e = 1; e < E_; ++e) if (lg[e] > lg[i0]) i0 = e;
        int i1 = -1;
        for (int e = 0; e < E_; ++e) {
            if (e == i0) continue;
            if (i1 < 0 || lg[e] > lg[i1]) i1 = e;
        }
        float e1 = __expf(lg[i1] - lg[i0]);
        float p0 = 1.f / (1.f + e1), p1 = e1 / (1.f + e1);
        int p, slot;
        p = atomicAdd(&counts[i0], 1);
        slot = atomicAdd(&counts[8], 1);
        etok[i0 * N_TOK + p] = n; eslot[i0 * N_TOK + p] = slot;
        tslot[n * 2 + 0] = slot; tscore[n * 2 + 0] = p0;
        p = atomicAdd(&counts[i1], 1);
        slot = atomicAdd(&counts[8], 1);
        etok[i1 * N_TOK + p] = n; eslot[i1 * N_TOK + p] = slot;
        tslot[n * 2 + 1] = slot; tscore[n * 2 + 1] = p1;
    }
}

// ---------------------------------------------------------------------------
// MoE up-proj: h1[slot] = gelu_tanh(nx[token] @ w1[e] + b1[e])
__global__ __launch_bounds__(256) void moe_gemm1(
    const float* __restrict__ nx, const float* __restrict__ w1, const float* __restrict__ b1,
    float* __restrict__ h1, const int* __restrict__ counts,
    const int* __restrict__ etok, const int* __restrict__ eslot) {
    int e = blockIdx.z;
    int cnt = counts[e];
    int m0 = blockIdx.y * 64;
    if (m0 >= cnt) return;
    int n0 = blockIdx.x * 64;
    const float* B = w1 + (size_t)e * D_ * MLPH;
    __shared__ float As[16][64];
    __shared__ float Bs[16][64];
    int tid = threadIdx.x;
    int tx = tid & 15, ty = tid >> 4;
    int lm = tid >> 2, lk4 = (tid & 3) * 4;
    int lkb = tid >> 4, lnb = (tid & 15) * 4;
    int p = m0 + lm;
    const float* Arow = (p < cnt) ? nx + (size_t)etok[e * N_TOK + p] * D_ : nullptr;
    float acc[4][4] = {};
    for (int k0 = 0; k0 < D_; k0 += 16) {
        float4 av = Arow ? *(const float4*)(Arow + k0 + lk4) : make_float4(0, 0, 0, 0);
        float4 bv = *(const float4*)(B + (size_t)(k0 + lkb) * MLPH + n0 + lnb);
        As[lk4 + 0][lm] = av.x; As[lk4 + 1][lm] = av.y;
        As[lk4 + 2][lm] = av.z; As[lk4 + 3][lm] = av.w;
        *(float4*)&Bs[lkb][lnb] = bv;
        __syncthreads();
#pragma unroll
        for (int k = 0; k < 16; ++k) {
            float a[4], b[4];
#pragma unroll
            for (int i = 0; i < 4; ++i) a[i] = As[k][ty * 4 + i];
#pragma unroll
            for (int j = 0; j < 4; ++j) b[j] = Bs[k][tx * 4 + j];
#pragma unroll
            for (int i = 0; i < 4; ++i)
#pragma unroll
                for (int j = 0; j < 4; ++j) acc[i][j] += a[i] * b[j];
        }
        __syncthreads();
    }
#pragma unroll
    for (int i = 0; i < 4; ++i) {
        int pr = m0 + ty * 4 + i;
        if (pr >= cnt) continue;
        int slot = eslot[e * N_TOK + pr];
        int col0 = n0 + tx * 4;
        float4 o;
        float* op = &o.x;
#pragma unroll
        for (int j = 0; j < 4; ++j) {
            float v = acc[i][j] + b1[e * MLPH + col0 + j];
            float u = 0.7978845608028654f * (v + 0.044715f * v * v * v);
            op[j] = 0.5f * v * (1.f + tanhf(u));
        }
        *(float4*)&h1[(size_t)slot * MLPH + col0] = o;
    }
}

// ---------------------------------------------------------------------------
// MoE down-proj: eo[slot] = h1[slot] @ w2[e] + b2[e]
__global__ __launch_bounds__(256) void moe_gemm2(
    const float* __restrict__ h1, const float* __restrict__ w2, const float* __restrict__ b2,
    float* __restrict__ eo, const int* __restrict__ counts, const int* __restrict__ eslot) {
    int e = blockIdx.z;
    int cnt = counts[e];
    int m0 = blockIdx.y * 64;
    if (m0 >= cnt) return;
    int n0 = blockIdx.x * 64;
    const float* B = w2 + (size_t)e * MLPH * D_;
    __shared__ float As[16][64];
    __shared__ float Bs[16][64];
    int tid = threadIdx.x;
    int tx = tid & 15, ty = tid >> 4;
    int lm = tid >> 2, lk4 = (tid & 3) * 4;
    int lkb = tid >> 4, lnb = (tid & 15) * 4;
    int p = m0 + lm;
    const float* Arow = (p < cnt) ? h1 + (size_t)eslot[e * N_TOK + p] * MLPH : nullptr;
    float acc[4][4] = {};
    for (int k0 = 0; k0 < MLPH; k0 += 16) {
        float4 av = Arow ? *(const float4*)(Arow + k0 + lk4) : make_float4(0, 0, 0, 0);
        float4 bv = *(const float4*)(B + (size_t)(k0 + lkb) * D_ + n0 + lnb);
        As[lk4 + 0][lm] = av.x; As[lk4 + 1][lm] = av.y;
        As[lk4 + 2][lm] = av.z; As[lk4 + 3][lm] = av.w;
        *(float4*)&Bs[lkb][lnb] = bv;
        __syncthreads();
#pragma unroll
        for (int k = 0; k < 16; ++k) {
            float a[4], b[4];
#pragma unroll
            for (int i = 0; i < 4; ++i) a[i] = As[k][ty * 4 + i];
#pragma unroll
            for (int j = 0; j < 4; ++j) b[j] = Bs[k][tx * 4 + j];
#pragma unroll
            for (int i = 0; i < 4; ++i)
#pragma unroll
                for (int j = 0; j < 4; ++j) acc[i][j] += a[i] * b[j];
        }
        __syncthreads();
    }
#pragma unroll
    for (int i = 0; i < 4; ++i) {
        int pr = m0 + ty * 4 + i;
        if (pr >= cnt) continue;
        int slot = eslot[e * N_TOK + pr];
        int col0 = n0 + tx * 4;
        float4 o;
        o.x = acc[i][0] + b2[e * D_ + col0 + 0];
        o.y = acc[i][1] + b2[e * D_ + col0 + 1];
        o.z = acc[i][2] + b2[e * D_ + col0 + 2];
        o.w = acc[i][3] + b2[e * D_ + col0 + 3];
        *(float4*)&eo[(size_t)slot * D_ + col0] = o;
    }
}

// ---------------------------------------------------------------------------
// out = xa + gate_mlp * (s0*eo[slot0] + s1*eo[slot1])
__global__ void combine_kernel(const float* __restrict__ xa, const float* __restrict__ eo,
                               const float* __restrict__ mod, const int* __restrict__ tslot,
                               const float* __restrict__ tscore, float* __restrict__ out) {
    int i = blockIdx.x * 256 + threadIdx.x;
    int n = i / D_, d = i % D_, b = n / S_;
    int s0 = tslot[n * 2 + 0], s1 = tslot[n * 2 + 1];
    float moe = tscore[n * 2 + 0] * eo[(size_t)s0 * D_ + d] +
                tscore[n * 2 + 1] * eo[(size_t)s1 * D_ + d];
    out[i] = xa[i] + mod[b * (4 * D_) + 3 * D_ + d] * moe;
}

__global__ void zero_counts(int* counts) {
    if (threadIdx.x < 16) counts[threadIdx.x] = 0;
}

// ---------------------------------------------------------------------------
extern "C" void kernel_launch(void* const* d_in, const int* in_sizes, int n_in,
                              void* d_out, int out_size, void* d_ws, size_t ws_size,
                              hipStream_t stream) {
    (void)in_sizes; (void)n_in; (void)out_size; (void)ws_size;
    const float* x       = (const float*)d_in[0];
    const float* c       = (const float*)d_in[1];
    const float* qkv_w   = (const float*)d_in[2];
    const float* qkv_b   = (const float*)d_in[3];
    const float* proj_w  = (const float*)d_in[4];
    const float* proj_b  = (const float*)d_in[5];
    const float* adaln_w = (const float*)d_in[6];
    const float* adaln_b = (const float*)d_in[7];
    const float* gate_w  = (const float*)d_in[8];
    const float* gate_b  = (const float*)d_in[9];
    const float* w1      = (const float*)d_in[10];
    const float* b1      = (const float*)d_in[11];
    const float* w2      = (const float*)d_in[12];
    const float* b2      = (const float*)d_in[13];

    float* ws = (float*)d_ws;
    // region plan (floats), with overlay: h1 reuses qkv/attn_o/o2 space
    float* mod  = ws;                         //      36864
    float* xa   = ws + 36864;                 //  2,359,296
    float* buf1 = ws + 2396160;               //  2,359,296  (h, later nx)
    float* qkvb = ws + 4755456;               //  7,077,888
    float* atto = ws + 11833344;              //  2,359,296
    float* o2   = ws + 14192640;              //  2,359,296
    float* h1   = ws + 4755456;               // 18,874,368 (after qkv/atto/o2 dead)
    float* eo   = ws + 23629824;              //  4,718,592 -> ends 28,348,416
    int*   counts = (int*)(ws + 28348416);    // 16
    int*   etok   = counts + 16;              // 16384
    int*   eslot  = etok + 16384;             // 16384
    int*   tslot  = eslot + 16384;            // 4096
    float* tscore = (float*)(tslot + 4096);   // 4096

    zero_counts<<<1, 64, 0, stream>>>(counts);
    adaln_kernel<<<dim3(18, 8), 256, 0, stream>>>(c, adaln_w, adaln_b, mod);
    ln_kernel<<<N_TOK, 256, 0, stream>>>(x, mod, buf1, 1);
    gemm_bias<<<dim3(3456 / 64, N_TOK / 64), 256, 0, stream>>>(buf1, qkv_w, qkv_b, qkvb,
                                                               N_TOK, 3456, D_);
    attn_kernel<<<dim3(16, H_, B_), 256, 0, stream>>>(qkvb, atto);
    gemm_bias<<<dim3(D_ / 64, N_TOK / 64), 256, 0, stream>>>(atto, proj_w, proj_b, o2,
                                                             N_TOK, D_, D_);
    residual1<<<(N_TOK * D_) / 256, 256, 0, stream>>>(x, o2, mod, xa);
    ln_kernel<<<N_TOK, 256, 0, stream>>>(xa, nullptr, buf1, 0);
    router_kernel<<<N_TOK, 64, 0, stream>>>(buf1, gate_w, gate_b, counts, etok, eslot,
                                            tslot, tscore);
    moe_gemm1<<<dim3(MLPH / 64, N_TOK / 64, E_), 256, 0, stream>>>(buf1, w1, b1, h1,
                                                                   counts, etok, eslot);
    moe_gemm2<<<dim3(D_ / 64, N_TOK / 64, E_), 256, 0, stream>>>(h1, w2, b2, eo,
                                                                 counts, eslot);
    combine_kernel<<<(N_TOK * D_) / 256, 256, 0, stream>>>(xa, eo, mod, tslot, tscore,
                                                           (float*)d_out);
}